// Round 3
// baseline (232.181 us; speedup 1.0000x reference)
//
#include <hip/hip_runtime.h>

#define BB 64
#define SS 512
#define HH 768
#define EE 128
#define TT 4
#define NP (EE * TT)        // 512 pairs
#define H4 (HH / 4)         // 192 float4 per row = blockDim
#define NPAIRBLK (BB * EE)  // 8192
#define NROWBLK (BB * SS)   // 32768

typedef float vf4 __attribute__((ext_vector_type(4)));  // nontemporal-storable

// ---------------------------------------------------------------------------
// Single fused kernel.
//   blocks [0, 8192):          pair blocks -> entity_embeddings[b,e,:]
//   blocks [8192, 8192+32768): row blocks  -> enhanced[b,s,:]
// Pair blocks RECOMPUTE the enhanced rows from hidden (no dependency on the
// row blocks' output), so everything fits in one launch with zero cross-block
// ordering requirements. Token->pair matching is done per-block via a 512-wide
// LDS scan of ent_tokens (2 KB, L2-broadcast) -- no global index structure.
// ---------------------------------------------------------------------------
__global__ __launch_bounds__(H4) void mega_kernel(
    const float* __restrict__ hidden,        // (B,S,H)
    const int* __restrict__ entity_types,    // (B,E)
    const float* __restrict__ conf,          // (B,E)
    const int* __restrict__ ent_tokens,      // (E,T)
    const float* __restrict__ type_table,    // (5,H)
    const float* __restrict__ conf_w,        // (H)
    const float* __restrict__ conf_b,        // (H)
    float* __restrict__ enhanced,            // (B,S,H)
    float* __restrict__ ee) {                // (B,E,H)
  __shared__ int ltok[NP];  // ent_tokens staged
  __shared__ int ml[NP];    // match list (pair ids) for current token
  __shared__ int nm;

  const int tid = threadIdx.x;  // 0..191

  // Stage all 512 tokens into LDS (covered by the first __syncthreads below).
  ltok[tid] = ent_tokens[tid];
  ltok[tid + 192] = ent_tokens[tid + 192];
  if (tid < NP - 384) ltok[tid + 384] = ent_tokens[tid + 384];

  // Per-column constants (tiny, L1-hot).
  const float4 wv = ((const float4*)conf_w)[tid];
  const float4 bv = ((const float4*)conf_b)[tid];

  if (blockIdx.x < NPAIRBLK) {
    // ---------------- pair block: one (b,e) -> ee row ----------------
    const int b = blockIdx.x >> 7;        // / EE
    const int e = blockIdx.x & (EE - 1);
    const int bE = b * EE;

    float4 aee = make_float4(0.f, 0.f, 0.f, 0.f);

    for (int t = 0; t < TT; ++t) {
      if (tid == 0) nm = 0;
      __syncthreads();  // covers staging (t==0) / previous compute (t>0)

      const int s = ltok[e * TT + t];
      if (ltok[tid] == s) ml[atomicAdd(&nm, 1)] = tid;
      if (ltok[tid + 192] == s) ml[atomicAdd(&nm, 1)] = tid + 192;
      if (tid < 128 && ltok[tid + 384] == s) ml[atomicAdd(&nm, 1)] = tid + 384;
      __syncthreads();

      const int cnt = nm;
      float4 acc = ((const float4*)(hidden + ((size_t)(b * SS + s)) * HH))[tid];
      for (int m = 0; m < cnt; ++m) {
        const int p = ml[m];
        const int ei = p >> 2;
        const int ty = entity_types[bE + ei];
        const float c = conf[bE + ei];
        const float4 tv = ((const float4*)(type_table + (size_t)ty * HH))[tid];
        acc.x += tv.x + fmaf(c, wv.x, bv.x);
        acc.y += tv.y + fmaf(c, wv.y, bv.y);
        acc.z += tv.z + fmaf(c, wv.z, bv.z);
        acc.w += tv.w + fmaf(c, wv.w, bv.w);
      }
      aee.x += acc.x;
      aee.y += acc.y;
      aee.z += acc.z;
      aee.w += acc.w;
      __syncthreads();  // protect ml/nm before next t resets them
    }

    vf4 o;
    o.x = aee.x * 0.25f;
    o.y = aee.y * 0.25f;
    o.z = aee.z * 0.25f;
    o.w = aee.w * 0.25f;
    __builtin_nontemporal_store(o, (vf4*)(ee + (size_t)(bE + e) * HH) + tid);
  } else {
    // ---------------- row block: one (b,s) -> enhanced row ----------------
    const int r = blockIdx.x - NPAIRBLK;  // b*S + s
    const int b = r >> 9;                 // / SS
    const int s = r & (SS - 1);
    const int bE = b * EE;

    if (tid == 0) nm = 0;
    __syncthreads();  // covers staging + nm reset

    if (ltok[tid] == s) ml[atomicAdd(&nm, 1)] = tid;
    if (ltok[tid + 192] == s) ml[atomicAdd(&nm, 1)] = tid + 192;
    if (tid < 128 && ltok[tid + 384] == s) ml[atomicAdd(&nm, 1)] = tid + 384;
    __syncthreads();

    const int cnt = nm;
    float4 acc = ((const float4*)(hidden + (size_t)r * HH))[tid];
    for (int m = 0; m < cnt; ++m) {
      const int p = ml[m];
      const int ei = p >> 2;
      const int ty = entity_types[bE + ei];
      const float c = conf[bE + ei];
      const float4 tv = ((const float4*)(type_table + (size_t)ty * HH))[tid];
      acc.x += tv.x + fmaf(c, wv.x, bv.x);
      acc.y += tv.y + fmaf(c, wv.y, bv.y);
      acc.z += tv.z + fmaf(c, wv.z, bv.z);
      acc.w += tv.w + fmaf(c, wv.w, bv.w);
    }
    // enhanced is never re-read by this kernel -> stream it out.
    vf4 ov;
    ov.x = acc.x;
    ov.y = acc.y;
    ov.z = acc.z;
    ov.w = acc.w;
    __builtin_nontemporal_store(ov, (vf4*)(enhanced + (size_t)r * HH) + tid);
  }
}

extern "C" void kernel_launch(void* const* d_in, const int* in_sizes, int n_in,
                              void* d_out, int out_size, void* d_ws,
                              size_t ws_size, hipStream_t stream) {
  const float* hidden = (const float*)d_in[0];
  const int* entity_types = (const int*)d_in[1];
  const float* conf = (const float*)d_in[2];
  const int* ent_tokens = (const int*)d_in[3];
  const float* type_table = (const float*)d_in[4];
  const float* conf_w = (const float*)d_in[5];
  const float* conf_b = (const float*)d_in[6];

  float* enhanced = (float*)d_out;                   // (B,S,H)
  float* ee = (float*)d_out + (size_t)BB * SS * HH;  // (B,E,H)

  mega_kernel<<<NPAIRBLK + NROWBLK, H4, 0, stream>>>(
      hidden, entity_types, conf, ent_tokens, type_table, conf_w, conf_b,
      enhanced, ee);
}